// Round 1
// baseline (196.688 us; speedup 1.0000x reference)
//
#include <hip/hip_runtime.h>
#include <math.h>

// One thread per batch element.
// Pipeline: closed-form 3x3 symmetric eigenvalues -> unrolled MLP (1->23->23->23->1,
// id-path + sum-path, ReLU between) -> spectral reconstruction via Newton divided
// differences (no eigenvectors needed):
//   out = ev_a*I + f[a,b]*(X - la*I) + f[a,b,c]*(X - la*I)(X - lb*I)

#define MLP_W 23

__device__ __forceinline__ float sinv(float d) {
    // guarded inverse: exact-tie eigenvalues give exact-tie MLP outputs, so
    // returning 0 for the 0/0 case yields the exactly-correct interpolant on
    // the actual spectrum.
    return (fabsf(d) > 1e-20f) ? (1.0f / d) : 0.0f;
}

__global__ __launch_bounds__(256, 2)
void svh_eig_mlp_kernel(
    const float* __restrict__ x,
    const float* __restrict__ wi0, const float* __restrict__ ws0, const float* __restrict__ bb0,
    const float* __restrict__ wi1, const float* __restrict__ ws1, const float* __restrict__ bb1,
    const float* __restrict__ wi2, const float* __restrict__ ws2, const float* __restrict__ bb2,
    const float* __restrict__ wi3, const float* __restrict__ ws3, const float* __restrict__ bb3,
    float* __restrict__ out, int B)
{
    int idx = blockIdx.x * blockDim.x + threadIdx.x;
    if (idx >= B) return;

    const float* xp = x + (size_t)idx * 9;
    float x00 = xp[0], x01 = xp[1], x02 = xp[2];
    float x11 = xp[4], x12 = xp[5], x22 = xp[8];

    // ---- closed-form symmetric 3x3 eigenvalues (trigonometric method) ----
    float q   = (x00 + x11 + x22) * (1.0f / 3.0f);
    float a00 = x00 - q, a11 = x11 - q, a22 = x22 - q;
    float p1  = x01 * x01 + x02 * x02 + x12 * x12;
    float p2  = a00 * a00 + a11 * a11 + a22 * a22 + 2.0f * p1;
    float p   = sqrtf(p2 * (1.0f / 6.0f));
    float ip  = sinv(p);
    float d00 = a00 * ip, d11 = a11 * ip, d22 = a22 * ip;
    float c01 = x01 * ip, c02 = x02 * ip, c12 = x12 * ip;
    float detB = d00 * (d11 * d22 - c12 * c12)
               - c01 * (c01 * d22 - c12 * c02)
               + c02 * (c01 * c12 - d11 * c02);
    float r = 0.5f * detB;
    r = fminf(1.0f, fmaxf(-1.0f, r));
    float phi  = acosf(r) * (1.0f / 3.0f);     // phi in [0, pi/3]
    float cph  = __cosf(phi);
    float sph  = sqrtf(fmaxf(0.0f, 1.0f - cph * cph)); // sin(phi) >= 0
    const float SQ3 = 1.7320508075688772f;
    float lc = q + 2.0f * p * cph;                // largest
    float la = q - p * cph - SQ3 * p * sph;       // smallest
    float lb = q - p * cph + SQ3 * p * sph;       // middle

    // ---- MLP on (la, lb, lc), permutation-equivariant ----
    float h[MLP_W][3];
    float g[MLP_W][3];

    // layer 0: ic = 1
    {
        float S = la + lb + lc;
#pragma unroll
        for (int o = 0; o < MLP_W; ++o) {
            float wi = wi0[o];
            float u  = fmaf(ws0[o], S, bb0[o]);
            h[o][0] = fmaxf(0.0f, fmaf(wi, la, u));
            h[o][1] = fmaxf(0.0f, fmaf(wi, lb, u));
            h[o][2] = fmaxf(0.0f, fmaf(wi, lc, u));
        }
    }

    // layer 1: h -> g
    {
        float s[MLP_W];
#pragma unroll
        for (int c = 0; c < MLP_W; ++c) s[c] = h[c][0] + h[c][1] + h[c][2];
#pragma unroll
        for (int o = 0; o < MLP_W; ++o) {
            float a0 = 0.0f, a1 = 0.0f, a2 = 0.0f, as = bb1[o];
#pragma unroll
            for (int c = 0; c < MLP_W; ++c) {
                float wi = wi1[o * MLP_W + c];
                float ws = ws1[o * MLP_W + c];
                a0 = fmaf(wi, h[c][0], a0);
                a1 = fmaf(wi, h[c][1], a1);
                a2 = fmaf(wi, h[c][2], a2);
                as = fmaf(ws, s[c], as);
            }
            g[o][0] = fmaxf(0.0f, a0 + as);
            g[o][1] = fmaxf(0.0f, a1 + as);
            g[o][2] = fmaxf(0.0f, a2 + as);
        }
    }

    // layer 2: g -> h
    {
        float s[MLP_W];
#pragma unroll
        for (int c = 0; c < MLP_W; ++c) s[c] = g[c][0] + g[c][1] + g[c][2];
#pragma unroll
        for (int o = 0; o < MLP_W; ++o) {
            float a0 = 0.0f, a1 = 0.0f, a2 = 0.0f, as = bb2[o];
#pragma unroll
            for (int c = 0; c < MLP_W; ++c) {
                float wi = wi2[o * MLP_W + c];
                float ws = ws2[o * MLP_W + c];
                a0 = fmaf(wi, g[c][0], a0);
                a1 = fmaf(wi, g[c][1], a1);
                a2 = fmaf(wi, g[c][2], a2);
                as = fmaf(ws, s[c], as);
            }
            h[o][0] = fmaxf(0.0f, a0 + as);
            h[o][1] = fmaxf(0.0f, a1 + as);
            h[o][2] = fmaxf(0.0f, a2 + as);
        }
    }

    // layer 3: oc = 1, no ReLU
    float eva, evb, evc;
    {
        float a0 = 0.0f, a1 = 0.0f, a2 = 0.0f, as = bb3[0];
#pragma unroll
        for (int c = 0; c < MLP_W; ++c) {
            float sc = h[c][0] + h[c][1] + h[c][2];
            float wi = wi3[c];
            a0 = fmaf(wi, h[c][0], a0);
            a1 = fmaf(wi, h[c][1], a1);
            a2 = fmaf(wi, h[c][2], a2);
            as = fmaf(ws3[c], sc, as);
        }
        eva = a0 + as;  // value at la
        evb = a1 + as;  // value at lb
        evc = a2 + as;  // value at lc
    }

    // ---- spectral reconstruction via Newton divided differences ----
    float g1 = (evb - eva) * sinv(lb - la);
    float g2 = (evc - evb) * sinv(lc - lb);
    float c2 = (g2 - g1) * sinv(lc - la);

    // M1 = X - la*I, M2 = X - lb*I; P = M1*M2 (symmetric)
    float m100 = x00 - la, m111 = x11 - la, m122 = x22 - la;
    float m200 = x00 - lb, m211 = x11 - lb, m222 = x22 - lb;

    float P00 = m100 * m200 + x01 * x01 + x02 * x02;
    float P01 = m100 * x01 + x01 * m211 + x02 * x12;
    float P02 = m100 * x02 + x01 * x12 + x02 * m222;
    float P11 = x01 * x01 + m111 * m211 + x12 * x12;
    float P12 = x01 * x02 + m111 * x12 + x12 * m222;
    float P22 = x02 * x02 + x12 * x12 + m122 * m222;

    float o00 = fmaf(g1, m100, eva) + c2 * P00;
    float o01 = g1 * x01 + c2 * P01;
    float o02 = g1 * x02 + c2 * P02;
    float o11 = fmaf(g1, m111, eva) + c2 * P11;
    float o12 = g1 * x12 + c2 * P12;
    float o22 = fmaf(g1, m122, eva) + c2 * P22;

    float* op = out + (size_t)idx * 9;
    op[0] = o00; op[1] = o01; op[2] = o02;
    op[3] = o01; op[4] = o11; op[5] = o12;
    op[6] = o02; op[7] = o12; op[8] = o22;
}

extern "C" void kernel_launch(void* const* d_in, const int* in_sizes, int n_in,
                              void* d_out, int out_size, void* d_ws, size_t ws_size,
                              hipStream_t stream) {
    const float* x   = (const float*)d_in[0];
    const float* wi0 = (const float*)d_in[1];
    const float* ws0 = (const float*)d_in[2];
    const float* b0  = (const float*)d_in[3];
    const float* wi1 = (const float*)d_in[4];
    const float* ws1 = (const float*)d_in[5];
    const float* b1  = (const float*)d_in[6];
    const float* wi2 = (const float*)d_in[7];
    const float* ws2 = (const float*)d_in[8];
    const float* b2  = (const float*)d_in[9];
    const float* wi3 = (const float*)d_in[10];
    const float* ws3 = (const float*)d_in[11];
    const float* b3  = (const float*)d_in[12];

    int B = in_sizes[0] / 9;
    float* out = (float*)d_out;

    dim3 block(256);
    dim3 grid((B + 255) / 256);
    hipLaunchKernelGGL(svh_eig_mlp_kernel, grid, block, 0, stream,
                       x, wi0, ws0, b0, wi1, ws1, b1, wi2, ws2, b2, wi3, ws3, b3,
                       out, B);
}

// Round 2
// 156.035 us; speedup vs baseline: 1.2605x; 1.2605x over previous
//
#include <hip/hip_runtime.h>
#include <math.h>

// One thread per batch element.
// Pipeline: closed-form 3x3 symmetric eigenvalues -> unrolled MLP (1->23->23->23->1,
// id-path + sum-path, ReLU between) -> spectral reconstruction via Newton divided
// differences (no eigenvectors needed).
//
// This round: packed-fp32 (v_pk_fma_f32) middle layers. The two 23x23 layers are
// repacked (by a prep kernel, into a module __device__ array) column-major as
// interleaved (wi, ws) float2 pairs so that:
//   (a0,a1) += (wi,wi) * (h0,h1)     -- op_sel-replicated sgpr pair
//   (a2,as) += (wi,ws) * (h2,s)      -- directly the packed sgpr pair
// halving VALU issue count for the dominant 2x2116 FMA stream.

#define MLP_W 23
typedef float v2f __attribute__((ext_vector_type(2)));

// two middle layers, col-major: pair index c*23+o holds (wi[o,c], ws[o,c])
__device__ v2f g_wpack[2 * MLP_W * MLP_W];

__global__ void svh_prep_kernel(const float* __restrict__ wi1, const float* __restrict__ ws1,
                                const float* __restrict__ wi2, const float* __restrict__ ws2) {
    int t = blockIdx.x * blockDim.x + threadIdx.x;
    const int n = MLP_W * MLP_W;
    if (t < n) {
        int c = t / MLP_W, o = t % MLP_W;
        g_wpack[t]     = (v2f){wi1[o * MLP_W + c], ws1[o * MLP_W + c]};
        g_wpack[n + t] = (v2f){wi2[o * MLP_W + c], ws2[o * MLP_W + c]};
    }
}

__device__ __forceinline__ float sinv(float d) {
    // guarded inverse: exact-tie eigenvalues give exact-tie MLP outputs, so the
    // 0/0 limit value never affects p(X) on the actual spectrum.
    return (fabsf(d) > 1e-20f) ? (1.0f / d) : 0.0f;
}

__global__ __launch_bounds__(256, 2)
void svh_eig_mlp_kernel(
    const float* __restrict__ x,
    const float* __restrict__ wi0, const float* __restrict__ ws0, const float* __restrict__ bb0,
    const float* __restrict__ bb1, const float* __restrict__ bb2,
    const float* __restrict__ wi3, const float* __restrict__ ws3, const float* __restrict__ bb3,
    float* __restrict__ out, int B)
{
    int idx = blockIdx.x * blockDim.x + threadIdx.x;
    if (idx >= B) return;

    const float* xp = x + (size_t)idx * 9;
    float x00 = xp[0], x01 = xp[1], x02 = xp[2];
    float x11 = xp[4], x12 = xp[5], x22 = xp[8];

    // ---- closed-form symmetric 3x3 eigenvalues (trigonometric method) ----
    float q   = (x00 + x11 + x22) * (1.0f / 3.0f);
    float a00 = x00 - q, a11 = x11 - q, a22 = x22 - q;
    float p1  = x01 * x01 + x02 * x02 + x12 * x12;
    float p2  = a00 * a00 + a11 * a11 + a22 * a22 + 2.0f * p1;
    float p   = sqrtf(p2 * (1.0f / 6.0f));
    float ip  = sinv(p);
    float d00 = a00 * ip, d11 = a11 * ip, d22 = a22 * ip;
    float c01 = x01 * ip, c02 = x02 * ip, c12 = x12 * ip;
    float detB = d00 * (d11 * d22 - c12 * c12)
               - c01 * (c01 * d22 - c12 * c02)
               + c02 * (c01 * c12 - d11 * c02);
    float r = 0.5f * detB;
    r = fminf(1.0f, fmaxf(-1.0f, r));
    float phi  = acosf(r) * (1.0f / 3.0f);     // phi in [0, pi/3]
    float cph  = __cosf(phi);
    float sph  = sqrtf(fmaxf(0.0f, 1.0f - cph * cph)); // sin(phi) >= 0
    const float SQ3 = 1.7320508075688772f;
    float lc = q + 2.0f * p * cph;                // largest
    float la = q - p * cph - SQ3 * p * sph;       // smallest
    float lb = q - p * cph + SQ3 * p * sph;       // middle

    // ---- MLP on (la, lb, lc), permutation-equivariant ----
    v2f   h01[MLP_W];   // (h[c][0], h[c][1])
    float h2 [MLP_W];   // h[c][2]

    // layer 0 (ic = 1)
    {
        float S = la + lb + lc;
#pragma unroll
        for (int o = 0; o < MLP_W; ++o) {
            float wi = wi0[o];
            float u  = fmaf(ws0[o], S, bb0[o]);
            float t0 = fmaxf(0.0f, fmaf(wi, la, u));
            float t1 = fmaxf(0.0f, fmaf(wi, lb, u));
            float t2 = fmaxf(0.0f, fmaf(wi, lc, u));
            h01[o] = (v2f){t0, t1};
            h2[o]  = t2;
        }
    }

    // middle layers: outer-product order over packed col-major (wi,ws) pairs
#pragma unroll
    for (int layer = 0; layer < 2; ++layer) {
        const v2f*   wpk  = &g_wpack[layer * MLP_W * MLP_W];
        const float* bias = (layer == 0) ? bb1 : bb2;

        v2f a01[MLP_W];   // (a0, a1)
        v2f a2s[MLP_W];   // (a2, as)

        // c = 0 peeled: init accumulators with a mul instead of zero-init
        {
            v2f hA = h01[0];
            float sc = hA.x + hA.y + h2[0];
            v2f hB = (v2f){h2[0], sc};
#pragma unroll
            for (int o = 0; o < MLP_W; ++o) {
                v2f w  = wpk[o];
                v2f ww = (v2f){w.x, w.x};
                a01[o] = ww * hA;
                a2s[o] = w * hB;
            }
        }
#pragma unroll
        for (int c = 1; c < MLP_W; ++c) {
            v2f hA = h01[c];
            float sc = hA.x + hA.y + h2[c];
            v2f hB = (v2f){h2[c], sc};
#pragma unroll
            for (int o = 0; o < MLP_W; ++o) {
                v2f w  = wpk[c * MLP_W + o];
                v2f ww = (v2f){w.x, w.x};
                a01[o] = __builtin_elementwise_fma(ww, hA, a01[o]);
                a2s[o] = __builtin_elementwise_fma(w,  hB, a2s[o]);
            }
        }
        // epilogue: add shared term + bias, ReLU, write back into h
#pragma unroll
        for (int o = 0; o < MLP_W; ++o) {
            float asb = a2s[o].y + bias[o];
            v2f  y01  = a01[o] + (v2f){asb, asb};
            float y2  = a2s[o].x + asb;
            v2f  z    = (v2f){0.0f, 0.0f};
            h01[o] = __builtin_elementwise_max(y01, z);
            h2[o]  = fmaxf(0.0f, y2);
        }
    }

    // layer 3 (oc = 1, no ReLU)
    float eva, evb, evc;
    {
        float a0 = 0.0f, a1 = 0.0f, a2 = 0.0f, as = bb3[0];
#pragma unroll
        for (int c = 0; c < MLP_W; ++c) {
            float t0 = h01[c].x, t1 = h01[c].y, t2 = h2[c];
            float sc = t0 + t1 + t2;
            float wi = wi3[c];
            a0 = fmaf(wi, t0, a0);
            a1 = fmaf(wi, t1, a1);
            a2 = fmaf(wi, t2, a2);
            as = fmaf(ws3[c], sc, as);
        }
        eva = a0 + as;  // value at la
        evb = a1 + as;  // value at lb
        evc = a2 + as;  // value at lc
    }

    // ---- spectral reconstruction via Newton divided differences ----
    float g1 = (evb - eva) * sinv(lb - la);
    float g2 = (evc - evb) * sinv(lc - lb);
    float c2 = (g2 - g1) * sinv(lc - la);

    float m100 = x00 - la, m111 = x11 - la, m122 = x22 - la;
    float m200 = x00 - lb, m211 = x11 - lb, m222 = x22 - lb;

    float P00 = m100 * m200 + x01 * x01 + x02 * x02;
    float P01 = m100 * x01 + x01 * m211 + x02 * x12;
    float P02 = m100 * x02 + x01 * x12 + x02 * m222;
    float P11 = x01 * x01 + m111 * m211 + x12 * x12;
    float P12 = x01 * x02 + m111 * x12 + x12 * m222;
    float P22 = x02 * x02 + x12 * x12 + m122 * m222;

    float o00 = fmaf(g1, m100, eva) + c2 * P00;
    float o01 = g1 * x01 + c2 * P01;
    float o02 = g1 * x02 + c2 * P02;
    float o11 = fmaf(g1, m111, eva) + c2 * P11;
    float o12 = g1 * x12 + c2 * P12;
    float o22 = fmaf(g1, m122, eva) + c2 * P22;

    float* op = out + (size_t)idx * 9;
    op[0] = o00; op[1] = o01; op[2] = o02;
    op[3] = o01; op[4] = o11; op[5] = o12;
    op[6] = o02; op[7] = o12; op[8] = o22;
}

extern "C" void kernel_launch(void* const* d_in, const int* in_sizes, int n_in,
                              void* d_out, int out_size, void* d_ws, size_t ws_size,
                              hipStream_t stream) {
    const float* x   = (const float*)d_in[0];
    const float* wi0 = (const float*)d_in[1];
    const float* ws0 = (const float*)d_in[2];
    const float* b0  = (const float*)d_in[3];
    const float* wi1 = (const float*)d_in[4];
    const float* ws1 = (const float*)d_in[5];
    const float* b1  = (const float*)d_in[6];
    const float* wi2 = (const float*)d_in[7];
    const float* ws2 = (const float*)d_in[8];
    const float* b2  = (const float*)d_in[9];
    const float* wi3 = (const float*)d_in[10];
    const float* ws3 = (const float*)d_in[11];
    const float* b3  = (const float*)d_in[12];

    int B = in_sizes[0] / 9;
    float* out = (float*)d_out;

    // repack middle-layer weights (col-major, interleaved (wi,ws) pairs)
    {
        int n = MLP_W * MLP_W;
        dim3 block(256);
        dim3 grid((n + 255) / 256);
        hipLaunchKernelGGL(svh_prep_kernel, grid, block, 0, stream, wi1, ws1, wi2, ws2);
    }

    dim3 block(256);
    dim3 grid((B + 255) / 256);
    hipLaunchKernelGGL(svh_eig_mlp_kernel, grid, block, 0, stream,
                       x, wi0, ws0, b0, b1, b2, wi3, ws3, b3,
                       out, B);
}